// Round 15
// baseline (566.801 us; speedup 1.0000x reference)
//
#include <hip/hip_runtime.h>
#include <stdint.h>

typedef __attribute__((ext_vector_type(8))) short bf8_t;   // 8 bf16 (4 VGPRs) MFMA A/B frag
typedef __attribute__((ext_vector_type(4))) float f4_t;    // MFMA C/D frag

#define DEVI static __device__ __forceinline__

// fp32 -> bf16 round-to-nearest-even
DEVI unsigned short f2b(float f) {
  unsigned u = __builtin_bit_cast(unsigned, f);
  u += 0x7fffu + ((u >> 16) & 1u);
  return (unsigned short)(u >> 16);
}

DEVI float b2f(unsigned short v) {
  return __builtin_bit_cast(float, (unsigned)v << 16);
}

// LDS-only block barrier: drain own LDS ops, then raw s_barrier. Unlike __syncthreads,
// does NOT wait vmcnt(0) -> global loads/stores stay in flight across phase boundaries.
DEVI void block_sync_lds() {
  asm volatile("s_waitcnt lgkmcnt(0)" ::: "memory");
  __builtin_amdgcn_s_barrier();
}

// ---------------------------------------------------------------- fused cast kernels
__global__ void cast_xy_k(const float* __restrict__ X, const float* __restrict__ Y,
                          ushort* __restrict__ Xb, ushort* __restrict__ Yb) {
  int i = blockIdx.x * 256 + threadIdx.x;
  const float* s;
  ushort* d;
  int off;
  if (i < 2097152) { s = X; d = Xb; off = i; }
  else             { s = Y; d = Yb; off = i - 2097152; }
  float4 v = reinterpret_cast<const float4*>(s)[off];
  ushort4 o;
  o.x = f2b(v.x); o.y = f2b(v.y); o.z = f2b(v.z); o.w = f2b(v.w);
  reinterpret_cast<ushort4*>(d)[off] = o;
}

__global__ void cast_w_k(const float* __restrict__ Wq, const float* __restrict__ Wk,
                         const float* __restrict__ Wv, const float* __restrict__ Wo,
                         ushort* __restrict__ o0, ushort* __restrict__ o1,
                         ushort* __restrict__ o2, ushort* __restrict__ o3, float sc) {
  int i = blockIdx.x * 256 + threadIdx.x;
  int which = i >> 18;
  int off = i & 262143;
  const float* s = which == 0 ? Wq : which == 1 ? Wk : which == 2 ? Wv : Wo;
  ushort* d = which == 0 ? o0 : which == 1 ? o1 : which == 2 ? o2 : o3;
  float scale = which == 0 ? sc : 1.0f;
  float4 v = reinterpret_cast<const float4*>(s)[off];
  ushort4 o;
  o.x = f2b(v.x * scale); o.y = f2b(v.y * scale); o.z = f2b(v.z * scale); o.w = f2b(v.w * scale);
  reinterpret_cast<ushort4*>(d)[off] = o;
}

// ---------------------------------------------------------------- mask bit-pack
__global__ void mask_pack_k(const int* __restrict__ mask, ushort* __restrict__ mp, int nwords) {
  int i = blockIdx.x * 256 + threadIdx.x;
  if (i >= nwords) return;
  const int4* src = reinterpret_cast<const int4*>(mask + (size_t)i * 16);
  unsigned v = 0;
#pragma unroll
  for (int j = 0; j < 4; j++) {
    int4 m = src[j];
    v |= ((unsigned)(m.x & 1) << (j * 4 + 0));
    v |= ((unsigned)(m.y & 1) << (j * 4 + 1));
    v |= ((unsigned)(m.z & 1) << (j * 4 + 2));
    v |= ((unsigned)(m.w & 1) << (j * 4 + 3));
  }
  mp[i] = (ushort)v;
}

// ---------------------------------------------------------------- GEMM: C[n][o] = sum_d A[n][d]*W[o][d] + bias[o]*bscale
// MODE 0: out bf16 row-major (8192x1024)
// MODE 2: out fp32 row-major
// MODE 3: K chunk-tiles: Kt[((b*128+mb)*16+h)*1024 + s*512 + r*32 + c32] -> attn k0/k1 DENSE 1KB
// MODE 4: V pv-tiles:  Vt[((b*16+h)*64+mc)*2048 + d*32 + m32] -> attn V loads DENSE 1KB x4
template<int MODE>
__global__ __launch_bounds__(256, 3) void gemm_bt(const ushort* __restrict__ A,
                                                  const ushort* __restrict__ W,
                                                  const float* __restrict__ bias,
                                                  void* __restrict__ outp, float bscale) {
  __shared__ ushort As[128 * 64];
  __shared__ ushort Ws[128 * 64];
  const int t = threadIdx.x;
  const int tileCol = blockIdx.x & 7;
  const int tileRow = blockIdx.x >> 3;
  const int rowBase = tileRow * 128;
  const int colBase = tileCol * 128;

  const int r32 = t >> 3;
  const int cu = t & 7;
  const int w = t >> 6;
  const int lane = t & 63;
  const int q = lane >> 4;
  const int c = lane & 15;
  const int wr = (w >> 1) * 64;
  const int wc = (w & 1) * 64;

  f4_t acc[4][4];
#pragma unroll
  for (int i = 0; i < 4; i++)
#pragma unroll
    for (int j = 0; j < 4; j++) acc[i][j] = (f4_t){0.f, 0.f, 0.f, 0.f};

  for (int k0 = 0; k0 < 1024; k0 += 64) {
#pragma unroll
    for (int rs = 0; rs < 4; rs++) {
      int r = rs * 32 + r32;
      int4 va = *reinterpret_cast<const int4*>(A + (size_t)(rowBase + r) * 1024 + k0 + cu * 8);
      int4 vw = *reinterpret_cast<const int4*>(W + (size_t)(colBase + r) * 1024 + k0 + cu * 8);
      *reinterpret_cast<int4*>(&As[r * 64 + ((cu ^ (r & 7)) << 3)]) = va;
      *reinterpret_cast<int4*>(&Ws[r * 64 + ((cu ^ (r & 7)) << 3)]) = vw;
    }
    __syncthreads();
    bf8_t af[4][2], bfr[4][2];
#pragma unroll
    for (int i = 0; i < 4; i++) {
      int ra = wr + i * 16 + c;
      int rb = wc + i * 16 + c;
#pragma unroll
      for (int s = 0; s < 2; s++) {
        af[i][s] = *reinterpret_cast<const bf8_t*>(&As[ra * 64 + (((s * 4 + q) ^ (ra & 7)) << 3)]);
        bfr[i][s] = *reinterpret_cast<const bf8_t*>(&Ws[rb * 64 + (((s * 4 + q) ^ (rb & 7)) << 3)]);
      }
    }
#pragma unroll
    for (int i = 0; i < 4; i++)
#pragma unroll
      for (int j = 0; j < 4; j++) {
        acc[i][j] = __builtin_amdgcn_mfma_f32_16x16x32_bf16(af[i][0], bfr[j][0], acc[i][j], 0, 0, 0);
        acc[i][j] = __builtin_amdgcn_mfma_f32_16x16x32_bf16(af[i][1], bfr[j][1], acc[i][j], 0, 0, 0);
      }
    __syncthreads();
  }

  // epilogue: D layout col=lane&15, row=(lane>>4)*4+reg  [measured m89/m91]
#pragma unroll
  for (int j = 0; j < 4; j++) {
    int col = colBase + wc + j * 16 + c;
    float bj = bias[col] * bscale;
#pragma unroll
    for (int i = 0; i < 4; i++) {
      int rbase = rowBase + wr + i * 16 + q * 4;
      if (MODE == 0) {
        ushort* out = (ushort*)outp;
#pragma unroll
        for (int reg = 0; reg < 4; reg++)
          out[(size_t)(rbase + reg) * 1024 + col] = f2b(acc[i][j][reg] + bj);
      } else if (MODE == 2) {
        float* out = (float*)outp;
#pragma unroll
        for (int reg = 0; reg < 4; reg++)
          out[(size_t)(rbase + reg) * 1024 + col] = acc[i][j][reg] + bj;
      } else if (MODE == 3) {
        ushort* out = (ushort*)outp;
        const int bb = rbase >> 11;
        const int mb = (rbase >> 4) & 127;
        const int h = col >> 6;
        const int s = (col >> 5) & 1;
        const int c32 = col & 31;
        ushort* tb = out + (((size_t)(bb * 128 + mb) * 16 + h) << 10) + s * 512 + c32;
#pragma unroll
        for (int reg = 0; reg < 4; reg++)
          tb[(size_t)((q * 4 + reg) * 32)] = f2b(acc[i][j][reg] + bj);
      } else {
        ushort* out = (ushort*)outp;
        const int bb = rbase >> 11;
        const int mc = (rbase >> 5) & 63;
        const int m32 = rbase & 31;
        const int h = col >> 6;
        const int d = col & 63;
        ushort4 v;
        v.x = f2b(acc[i][j][0] + bj);
        v.y = f2b(acc[i][j][1] + bj);
        v.z = f2b(acc[i][j][2] + bj);
        v.w = f2b(acc[i][j][3] + bj);
        *reinterpret_cast<ushort4*>(out + ((((size_t)(bb * 16 + h) * 64 + mc) << 11) + d * 32 + m32)) = v;
      }
    }
  }
}

// ---------------------------------------------------------------- fused attention: 32 q-rows/block, P in LDS, dense K/V
// Block: one (b,h), 32 q-rows, 512 threads; 8 waves x 256-col m-strips; each wave handles
// TWO 16-row groups that SHARE every K/V load (4 QK MFMAs per 1KB K load, 8 PV MFMAs per
// 4KB V tile) -> K/V load count per unit work HALVED vs R14; barriers/merge/l-reduce
// amortized 2x. LDS: P[8][32][256]bf16 = 128KB -> 1 block/CU, 8 waves (occupancy 25%).
// __launch_bounds__(512,2): VGPR cap 256 -> no spill (regs ~220). R10 showed high occupancy
// is not protective here; trading it for 2x ILP + half the loads.
__global__ __launch_bounds__(512, 2) void attn_k(const ushort* __restrict__ Qb,
                                                 const ushort* __restrict__ Kt,
                                                 const ushort* __restrict__ Vt,
                                                 const ushort* __restrict__ Mp,
                                                 float* __restrict__ beta,
                                                 ushort* __restrict__ Cc) {
  __shared__ ushort Pl[8 * 32 * 256];  // 128KB: P strips [w][32 rows][256 cols], 16B-unit swizzled
  __shared__ float lpart[8][32];
  float* OwU = (float*)Pl;             // union: Ow[8][32][68] (69.6KB) after P consumed

  const int L = blockIdx.x;            // 4096 blocks
  const int bh = (L >> 9) * 8 + (L & 7);  // 0..63, low 3 bits pin XCD
  const int qt = (L >> 3) & 63;
  const int b = bh >> 4;
  const int h = bh & 15;
  const int n0 = qt * 32;

  const int t = threadIdx.x;
  const int w = t >> 6;    // 0..7
  const int lane = t & 63;
  const int q = lane >> 4;
  const int c = lane & 15;
  const int dlo = (c * 4 + q) * 8;  // dense lane offset: 64 lanes -> 1KB

  // Q frags for both row-groups (rows n0+c and n0+16+c)
  const size_t qbase = ((size_t)(b * 2048 + n0 + c)) * 1024 + h * 64 + q * 8;
  bf8_t qaA0 = *reinterpret_cast<const bf8_t*>(Qb + qbase);
  bf8_t qaA1 = *reinterpret_cast<const bf8_t*>(Qb + qbase + 32);
  bf8_t qaB0 = *reinterpret_cast<const bf8_t*>(Qb + qbase + 16 * 1024);
  bf8_t qaB1 = *reinterpret_cast<const bf8_t*>(Qb + qbase + 16 * 1024 + 32);

  const size_t ktbase = ((size_t)((b * 128 + w * 16) * 16 + h)) << 10;
  const size_t vtbase = ((size_t)((b * 16 + h) * 64 + w * 8)) << 11;
  const int mBase = w * 256;
  const ushort* mpk = Mp + ((size_t)(b * 2048 + n0)) * 128 + (mBase >> 4);
  ushort* Ps = Pl + w * (32 * 256);  // this wave's strip

  // ---- pass 1: QK sweep, 2 row-groups per K load; e -> LDS strip; l accum
  float ls[8] = {0.f, 0.f, 0.f, 0.f, 0.f, 0.f, 0.f, 0.f};

  int4 mrow[2][2][4];  // [half g][row-group][reg]
#pragma unroll
  for (int g = 0; g < 2; ++g)
#pragma unroll
    for (int rg = 0; rg < 2; ++rg)
#pragma unroll
      for (int r = 0; r < 4; r++)
        mrow[g][rg][r] = *reinterpret_cast<const int4*>(
            mpk + (size_t)(rg * 16 + q * 4 + r) * 128 + g * 8);

  bf8_t kpf[3][2];
  {
    const ushort* kp0 = Kt + ktbase + dlo;
    kpf[0][0] = *reinterpret_cast<const bf8_t*>(kp0);
    kpf[0][1] = *reinterpret_cast<const bf8_t*>(kp0 + 512);
    const ushort* kp1 = Kt + ktbase + (1 << 14) + dlo;
    kpf[1][0] = *reinterpret_cast<const bf8_t*>(kp1);
    kpf[1][1] = *reinterpret_cast<const bf8_t*>(kp1 + 512);
  }

#pragma unroll
  for (int mb = 0; mb < 16; ++mb) {
    if (mb < 14) {
      const ushort* kp = Kt + ktbase + ((size_t)(mb + 2) << 14) + dlo;
      kpf[(mb + 2) % 3][0] = *reinterpret_cast<const bf8_t*>(kp);
      kpf[(mb + 2) % 3][1] = *reinterpret_cast<const bf8_t*>(kp + 512);
    }
    f4_t sA = (f4_t){0.f, 0.f, 0.f, 0.f};
    f4_t sB = (f4_t){0.f, 0.f, 0.f, 0.f};
    sA = __builtin_amdgcn_mfma_f32_16x16x32_bf16(qaA0, kpf[mb % 3][0], sA, 0, 0, 0);
    sB = __builtin_amdgcn_mfma_f32_16x16x32_bf16(qaB0, kpf[mb % 3][0], sB, 0, 0, 0);
    sA = __builtin_amdgcn_mfma_f32_16x16x32_bf16(qaA1, kpf[mb % 3][1], sA, 0, 0, 0);
    sB = __builtin_amdgcn_mfma_f32_16x16x32_bf16(qaB1, kpf[mb % 3][1], sB, 0, 0, 0);
    const int g = mb >> 3;
    const int mi = mb & 7;
    const int u = mb * 2 + (c >> 3);
#pragma unroll
    for (int rg = 0; rg < 2; ++rg) {
      f4_t s = rg ? sB : sA;
#pragma unroll
      for (int reg = 0; reg < 4; reg++) {
        const int row = rg * 16 + q * 4 + reg;
        unsigned mword = (unsigned)((mi >> 1) == 0 ? mrow[g][rg][reg].x
                                  : (mi >> 1) == 1 ? mrow[g][rg][reg].y
                                  : (mi >> 1) == 2 ? mrow[g][rg][reg].z
                                                   : mrow[g][rg][reg].w);
        unsigned masked = (mword >> ((mi & 1) * 16 + c)) & 1u;
        float e = masked ? 0.f : __builtin_amdgcn_exp2f(s[reg]);
        ls[rg * 4 + reg] += e;
        Ps[row * 256 + (((u ^ (row & 7)) << 3) | (c & 7))] = f2b(e);
      }
    }
  }

  // ---- issue V for p=0 BEFORE the barrier (stays in flight across it)
  bf8_t vpf[2][4];
  {
    const ushort* vp = Vt + vtbase + dlo;
#pragma unroll
    for (int db = 0; db < 4; db++) vpf[0][db] = *reinterpret_cast<const bf8_t*>(vp + db * 512);
  }

  // ---- l reduce -> lpart (both row-groups)
#pragma unroll
  for (int i = 0; i < 8; i++) {
    ls[i] += __shfl_xor(ls[i], 1);
    ls[i] += __shfl_xor(ls[i], 2);
    ls[i] += __shfl_xor(ls[i], 4);
    ls[i] += __shfl_xor(ls[i], 8);
  }
  if (c == 0) {
#pragma unroll
    for (int i = 0; i < 8; i++) lpart[w][(i >> 2) * 16 + q * 4 + (i & 3)] = ls[i];
  }
  block_sync_lds();  // P strips + lpart visible; V loads remain in flight

  // ---- pass 2: PV (2 row-groups share V, double-buffered) + DENSE beta (4 rows/wave)
  f4_t o[2][4];
#pragma unroll
  for (int rg = 0; rg < 2; ++rg)
#pragma unroll
    for (int db = 0; db < 4; db++) o[rg][db] = (f4_t){0.f, 0.f, 0.f, 0.f};

  const int br = 4 * w + (lane >> 5);      // rows br and br+2 for this lane
  const int j2 = lane & 31;
  float ls0 = 0.f, ls1 = 0.f;
#pragma unroll
  for (int ww = 0; ww < 8; ww++) { ls0 += lpart[ww][br]; ls1 += lpart[ww][br + 2]; }
  const float li0 = 1.0f / ls0;
  const float li1 = 1.0f / ls1;
  float* brow0 = beta + ((size_t)(bh * 2048 + n0 + br)) * 2048;
  float* brow1 = beta + ((size_t)(bh * 2048 + n0 + br + 2)) * 2048;

#pragma unroll
  for (int p = 0; p < 8; ++p) {
    if (p < 7) {
      const ushort* vp = Vt + vtbase + ((size_t)(p + 1) << 11) + dlo;
#pragma unroll
      for (int db = 0; db < 4; db++)
        vpf[(p + 1) & 1][db] = *reinterpret_cast<const bf8_t*>(vp + db * 512);
    }
    const int u = p * 4 + q;
    bf8_t paA = *reinterpret_cast<const bf8_t*>(&Ps[c * 256 + ((u ^ (c & 7)) << 3)]);
    bf8_t paB = *reinterpret_cast<const bf8_t*>(&Ps[(16 + c) * 256 + ((u ^ ((16 + c) & 7)) << 3)]);
    __builtin_amdgcn_s_setprio(1);
#pragma unroll
    for (int db = 0; db < 4; db++) {
      o[0][db] = __builtin_amdgcn_mfma_f32_16x16x32_bf16(paA, vpf[p & 1][db], o[0][db], 0, 0, 0);
      o[1][db] = __builtin_amdgcn_mfma_f32_16x16x32_bf16(paB, vpf[p & 1][db], o[1][db], 0, 0, 0);
    }
    __builtin_amdgcn_s_setprio(0);
    // beta: cols k=2p,2p+1 (128 floats each) x 2 row-pairs
#pragma unroll
    for (int kk = 0; kk < 2; ++kk) {
      const int k = p * 2 + kk;
      const int s = k >> 1;                       // source strip (= p)
      const int off = (k & 1) * 128 + j2 * 4;
      const int uu = off >> 3;
      const int e4 = off & 7;
#pragma unroll
      for (int rp = 0; rp < 2; ++rp) {
        const int row = br + rp * 2;
        ushort4 pv4 = *reinterpret_cast<const ushort4*>(
            &Pl[s * 8192 + row * 256 + ((uu ^ (row & 7)) << 3) + e4]);
        const float li = rp ? li1 : li0;
        float* brow = rp ? brow1 : brow0;
        float4 f;
        f.x = b2f(pv4.x) * li;
        f.y = b2f(pv4.y) * li;
        f.z = b2f(pv4.z) * li;
        f.w = b2f(pv4.w) * li;
        *reinterpret_cast<float4*>(brow + k * 128 + j2 * 4) = f;
      }
    }
  }

  block_sync_lds();  // all P reads done -> safe to overwrite with Ow

  // ---- merge O across 8 waves via union region, scale by 1/l, store concat bf16
#pragma unroll
  for (int rg = 0; rg < 2; ++rg)
#pragma unroll
    for (int db = 0; db < 4; db++)
#pragma unroll
      for (int reg = 0; reg < 4; reg++)
        OwU[(w * 32 + rg * 16 + q * 4 + reg) * 68 + db * 16 + c] = o[rg][db][reg];
  block_sync_lds();
  {
    int r = t >> 4;            // 0..31
    int d0 = (t & 15) * 4;
    float lsum = 0.f;
#pragma unroll
    for (int ww = 0; ww < 8; ww++) lsum += lpart[ww][r];
    float sl = 1.0f / lsum;
    float4 acc = (float4){0.f, 0.f, 0.f, 0.f};
#pragma unroll
    for (int ww = 0; ww < 8; ww++) {
      float4 sv = *reinterpret_cast<const float4*>(&OwU[(ww * 32 + r) * 68 + d0]);
      acc.x += sv.x; acc.y += sv.y; acc.z += sv.z; acc.w += sv.w;
    }
    ushort4 ov;
    ov.x = f2b(acc.x * sl);
    ov.y = f2b(acc.y * sl);
    ov.z = f2b(acc.z * sl);
    ov.w = f2b(acc.w * sl);
    *reinterpret_cast<ushort4*>(Cc + ((size_t)(b * 2048 + n0 + r)) * 1024 + h * 64 + d0) = ov;
  }
}

// ---------------------------------------------------------------- launch
extern "C" void kernel_launch(void* const* d_in, const int* in_sizes, int n_in,
                              void* d_out, int out_size, void* d_ws, size_t ws_size,
                              hipStream_t stream) {
  (void)in_sizes; (void)n_in; (void)out_size; (void)ws_size;
  const float* X = (const float*)d_in[0];
  const float* Y = (const float*)d_in[1];
  const int* mask = (const int*)d_in[2];
  const float* Wq = (const float*)d_in[3];
  const float* bq = (const float*)d_in[4];
  const float* Wk = (const float*)d_in[5];
  const float* bk = (const float*)d_in[6];
  const float* Wv = (const float*)d_in[7];
  const float* bv = (const float*)d_in[8];
  const float* Wo = (const float*)d_in[9];
  const float* bo = (const float*)d_in[10];
  float* out = (float*)d_out;

  const float SC = 0.18033688011112042f;  // (1/sqrt(64)) * log2(e), folded into Wq/bq

  char* ws = (char*)d_ws;
  const size_t SZ = 16777216;  // 8192*1024*2B
  ushort* Xb = (ushort*)(ws);
  ushort* Yb = (ushort*)(ws + SZ);
  ushort* Qb = (ushort*)(ws + 2 * SZ);
  ushort* Kb = (ushort*)(ws + 3 * SZ);   // K chunk-tiles
  ushort* Vt = (ushort*)(ws + 4 * SZ);   // V pv-tiles
  ushort* Cc = (ushort*)(ws + 5 * SZ);
  ushort* Wqb = (ushort*)(ws + 6 * SZ);
  ushort* Wkb = (ushort*)(ws + 6 * SZ + 2097152);
  ushort* Wvb = (ushort*)(ws + 6 * SZ + 2 * 2097152);
  ushort* Wob = (ushort*)(ws + 6 * SZ + 3 * 2097152);
  ushort* Mp  = (ushort*)(ws + 6 * SZ + 4 * 2097152);  // 2 MB packed mask

  cast_xy_k<<<16384, 256, 0, stream>>>(X, Y, Xb, Yb);
  cast_w_k<<<4096, 256, 0, stream>>>(Wq, Wk, Wv, Wo, Wqb, Wkb, Wvb, Wob, SC);
  mask_pack_k<<<4096, 256, 0, stream>>>(mask, Mp, 1048576);

  gemm_bt<0><<<512, 256, 0, stream>>>(Xb, Wqb, bq, (void*)Qb, SC);
  gemm_bt<3><<<512, 256, 0, stream>>>(Yb, Wkb, bk, (void*)Kb, 1.0f);
  gemm_bt<4><<<512, 256, 0, stream>>>(Yb, Wvb, bv, (void*)Vt, 1.0f);

  attn_k<<<4096, 512, 0, stream>>>(Qb, Kb, Vt, Mp, out + 8388608, Cc);

  gemm_bt<2><<<512, 256, 0, stream>>>(Cc, Wob, bo, (void*)out, 1.0f);
}